// Round 16
// baseline (223.995 us; speedup 1.0000x reference)
//
#include <hip/hip_runtime.h>
#include <stdint.h>

// Problem constants
#define S_LEN   2048
#define D_MODEL 1024
#define N_HEADS 16
#define HEAD_D  64
#define BATCH   2
#define M_TOT   (BATCH * S_LEN)   // 4096 rows for the QKV projection GEMM

typedef __attribute__((ext_vector_type(8))) short s8v;            // 8 x bf16 (MFMA A/B frag)
typedef __attribute__((ext_vector_type(4))) float f4v;            // 4 x f32  (MFMA C/D frag)
typedef __attribute__((ext_vector_type(4))) unsigned short u4v;   // 4 x bf16 packed

__device__ __forceinline__ float bf2f(unsigned short u) {
    union { unsigned int i; float f; } c; c.i = ((unsigned int)u) << 16; return c.f;
}
__device__ __forceinline__ unsigned short f2bf(float f) {
    union { float f; unsigned int i; } c; c.f = f;
    unsigned int u = c.i + 0x7FFFu + ((c.i >> 16) & 1u);   // round-nearest-even
    return (unsigned short)(u >> 16);
}
__device__ __forceinline__ unsigned int pk2bf(float lo, float hi) {
    return (unsigned int)f2bf(lo) | ((unsigned int)f2bf(hi) << 16);
}
// exp2 via the HW transcendental (v_exp_f32)
__device__ __forceinline__ float hw_exp2(float x) { return __builtin_amdgcn_exp2f(x); }

// async global->LDS, 16B per lane; LDS dest is wave-uniform base (+lane*16 implicit)
#define GLD16(gp, lp) __builtin_amdgcn_global_load_lds(                      \
    (const __attribute__((address_space(1))) void*)(const void*)(gp),        \
    (__attribute__((address_space(3))) void*)(void*)(lp), 16, 0, 0)

// barrier WITHOUT draining vmcnt (prefetches stay in flight) but WITH lgkmcnt
// drain (R5 race fix: no wave signals the barrier with ds_reads outstanding).
#define BAR_LGKM() asm volatile("s_waitcnt lgkmcnt(0)\n\ts_barrier" ::: "memory")

// exp(x*0.125) == exp2(x * 0.125*log2(e))
#define EXP_SCALE 0.1803368801111204f

// ---------------- kernel 0: fp32 -> bf16 conversion, ALL inputs in one launch ----
#define N_X (M_TOT * D_MODEL)
#define N_W (D_MODEL * D_MODEL)
__global__ __launch_bounds__(256) void cvt_all(
    const float* __restrict__ x,  const float* __restrict__ wq,
    const float* __restrict__ wk, const float* __restrict__ wv,
    unsigned short* __restrict__ xb,  unsigned short* __restrict__ wqb,
    unsigned short* __restrict__ wkb, unsigned short* __restrict__ wvb) {
    const int total4 = (N_X + 3 * N_W) / 4;
    for (int i4 = blockIdx.x * 256 + threadIdx.x; i4 < total4;
         i4 += gridDim.x * 256) {
        const int i = i4 * 4;
        const float* s; unsigned short* d; int off;
        if (i < N_X)               { s = x;  d = xb;  off = i; }
        else if (i < N_X + N_W)    { s = wq; d = wqb; off = i - N_X; }
        else if (i < N_X + 2*N_W)  { s = wk; d = wkb; off = i - N_X - N_W; }
        else                       { s = wv; d = wvb; off = i - N_X - 2*N_W; }
        float4 v = *(const float4*)(s + off);
        u4v o;
        o[0] = f2bf(v.x); o[1] = f2bf(v.y); o[2] = f2bf(v.z); o[3] = f2bf(v.w);
        *(u4v*)(d + off) = o;
    }
}

// ---------------- kernel 1: QKV projection GEMM (m97 structure) ----------------
__global__ __launch_bounds__(256) void qkv_gemm(
    const unsigned short* __restrict__ X,
    const unsigned short* __restrict__ Wq, const unsigned short* __restrict__ Wk,
    const unsigned short* __restrict__ Wv,
    const float* __restrict__ bq, const float* __restrict__ bk, const float* __restrict__ bv,
    unsigned short* __restrict__ q_ws, unsigned short* __restrict__ k_ws,
    unsigned short* __restrict__ vt_ws) {
    __shared__ unsigned short sA[128 * 32];
    __shared__ unsigned short sB[128 * 32];

    const int z = blockIdx.z;
    const unsigned short* Wm = (z == 0) ? Wq : ((z == 1) ? Wk : Wv);
    const float* bm = (z == 0) ? bq : ((z == 1) ? bk : bv);
    const int m0 = blockIdx.x * 128, n0 = blockIdx.y * 128;
    const int t = threadIdx.x;
    const int lane = t & 63, w = t >> 6;
    const int fr = lane & 15, g = lane >> 4;
    const int wr = w >> 1, wc = w & 1;

    f4v acc[4][4];
#pragma unroll
    for (int i = 0; i < 4; ++i)
#pragma unroll
        for (int j = 0; j < 4; ++j) acc[i][j] = (f4v){0.f, 0.f, 0.f, 0.f};

    const int rowL = t >> 2;
    const int colL = (t & 3) * 8;
    const unsigned short* gA = X + (size_t)(m0 + rowL) * D_MODEL + colL;
    const unsigned short* gB = Wm + (size_t)(n0 + rowL) * D_MODEL + colL;

    for (int kb = 0; kb < 32; ++kb) {
        const int k0 = kb * 32;
        GLD16(gA + k0,                 sA + w * 512);
        GLD16(gA + 64 * D_MODEL + k0,  sA + 2048 + w * 512);
        GLD16(gB + k0,                 sB + w * 512);
        GLD16(gB + 64 * D_MODEL + k0,  sB + 2048 + w * 512);
        __syncthreads();

        s8v af[4], bfv[4];
#pragma unroll
        for (int i = 0; i < 4; ++i)
            af[i] = *(const s8v*)(sA + (wr * 64 + i * 16 + fr) * 32 + g * 8);
#pragma unroll
        for (int j = 0; j < 4; ++j)
            bfv[j] = *(const s8v*)(sB + (wc * 64 + j * 16 + fr) * 32 + g * 8);
#pragma unroll
        for (int i = 0; i < 4; ++i)
#pragma unroll
            for (int j = 0; j < 4; ++j)
                acc[i][j] = __builtin_amdgcn_mfma_f32_16x16x32_bf16(af[i], bfv[j], acc[i][j], 0, 0, 0);
        __syncthreads();
    }

    const int e_base = n0 + wc * 64;
    const int m_base = m0 + wr * 64;
    if (z < 2) {
        unsigned short* dst = (z == 0) ? q_ws : k_ws;
#pragma unroll
        for (int i = 0; i < 4; ++i) {
#pragma unroll
            for (int j = 0; j < 4; ++j) {
                const int e = e_base + j * 16 + fr;
                const int h = e >> 6, dh = e & 63;
                const float bias = bm[e];
                const int mr = m_base + i * 16 + g * 4;
                const int b_ = mr >> 11, srow = mr & 2047;
                const size_t base = (((size_t)(b_ * N_HEADS + h) * S_LEN + srow) << 6) + dh;
#pragma unroll
                for (int r = 0; r < 4; ++r)
                    dst[base + ((size_t)r << 6)] = f2bf(acc[i][j][r] + bias);
            }
        }
    } else {
#pragma unroll
        for (int i = 0; i < 4; ++i) {
#pragma unroll
            for (int j = 0; j < 4; ++j) {
                const int e = e_base + j * 16 + fr;
                const int h = e >> 6, dh = e & 63;
                const float bias = bm[e];
                const int mr = m_base + i * 16 + g * 4;
                const int b_ = mr >> 11, srow = mr & 2047;
                u4v pk;
#pragma unroll
                for (int r = 0; r < 4; ++r) pk[r] = f2bf(acc[i][j][r] + bias);
                *(u4v*)(vt_ws + ((size_t)(b_ * N_HEADS + h) * HEAD_D + dh) * S_LEN + srow) = pk;
            }
        }
    }
}

// ---------------- kernel 2: fused attention (R15 + barrier-free phase 1) --------
// R16 = R15 with phase 1 converted to DIRECT-from-global fragment reads:
// rowsum(t0) needs each lane's K fragments exactly once; K is L2-resident
// (16 WGs/head x 256KB, 2MB/XCD). No LDS, no barriers, no vmcnt choreography —
// 8 independent waves/CU + unroll-4 (compiler schedules ~16 loads ahead) hide
// L2 latency. vmcnt(0) pin after the loop keeps phase-2/3 manual counts exact.
//  phase 1:            direct K fragment reads, rowsum(t0), barrier-free.
//  phase 2 (16 iters): K128+V128 staged, pass B(t0) + rowsum(t1) interleaved.
//  phase 3 (16 iters): pass B(t1).
// Weight stores: cooperative from PL, 8 x 256B contiguous NT per lane per iter
// (R10 rule: never scatter the 540MB stream below 256B segments).
// vmcnt (m135 oldest-first): ph2,3 c==0:8, steady:16, last:8.
// LDS 80KB -> 2 WG/CU (8 waves/CU, proven sufficient in R11/R12).
__global__ __launch_bounds__(256, 2) void attn_fused12(
    const unsigned short* __restrict__ q_ws, const unsigned short* __restrict__ k_ws,
    const unsigned short* __restrict__ vt_ws,
    float* __restrict__ out, float* __restrict__ wts) {
    __shared__ __align__(16) char SM[81920];
    // phases 2/3: K[buf] = SM + buf*16384 ; V[buf] = SM + 32768 + buf*16384
    //             PL = SM + 65536 + w*4096       ([16 q][128 keys] bf16, swizzled)

    const int t = threadIdx.x, lane = t & 63, w = t >> 6;
    const int fr = lane & 15, g = lane >> 4;
    const int blk = blockIdx.x;
    // 512 WGs: bits [2:0]=xcd, [6:3]=tile-pair, [8:7]=bh-within-xcd (bijective)
    const int bh = (blk & 7) * 4 + (blk >> 7);
    const int tp = (blk >> 3) & 15;
    const int q0 = tp * 128 + w * 16;        // tile0 rows (this wave)
    const int q1 = q0 + 64;                  // tile1 rows

    const unsigned short* Kp = k_ws + (size_t)bh * S_LEN * HEAD_D;
    const unsigned short* Vt = vt_ws + (size_t)bh * HEAD_D * S_LEN;
    const unsigned short* Qp0 = q_ws + ((size_t)bh * S_LEN + q0) * HEAD_D;
    const unsigned short* Qp1 = q_ws + ((size_t)bh * S_LEN + q1) * HEAD_D;

    const s8v qa00 = *(const s8v*)(Qp0 + fr * HEAD_D + g * 8);
    const s8v qa01 = *(const s8v*)(Qp0 + fr * HEAD_D + 32 + g * 8);
    const s8v qa10 = *(const s8v*)(Qp1 + fr * HEAD_D + g * 8);
    const s8v qa11 = *(const s8v*)(Qp1 + fr * HEAD_D + 32 + g * 8);

    // K chunks: [keys][64 dh] bf16, 128B rows, blk^=row&7 source pre-swizzle
    auto stageK128 = [&](int c, char* dst) {
#pragma unroll
        for (int j = 0; j < 4; ++j) {
            const int d = t * 16 + j * 4096;
            const int row = d >> 7, cb = (d >> 4) & 7;
            GLD16(Kp + (size_t)(c * 128 + row) * HEAD_D + ((cb ^ (row & 7)) << 3),
                  dst + w * 1024 + j * 4096);
        }
    };
    // V128 chunk (16KB): [64 dh][128 keys], 256B rows, blk^=row&15 pre-swizzle
    auto stageV128 = [&](int c, char* dst) {
#pragma unroll
        for (int j = 0; j < 4; ++j) {
            const int d = t * 16 + j * 4096;
            const int row = d >> 8, cb = (d >> 4) & 15;
            GLD16(Vt + (size_t)row * S_LEN + c * 128 + ((cb ^ (row & 15)) << 3),
                  dst + w * 1024 + j * 4096);
        }
    };
    // swapped QK^T, one 16-key subtile from LDS: reg r = S[key st*16+g*4+r][q=fr]
    auto qk16 = [&](const char* kb, int st, const s8v& a0, const s8v& a1) -> f4v {
        const int row = st * 16 + fr, m = row & 7;
        const s8v ka0 = *(const s8v*)(kb + row * 128 + ((g ^ m) << 4));
        const s8v ka1 = *(const s8v*)(kb + row * 128 + (((4 + g) ^ m) << 4));
        f4v s = (f4v){0.f, 0.f, 0.f, 0.f};
        s = __builtin_amdgcn_mfma_f32_16x16x32_bf16(ka0, a0, s, 0, 0, 0);
        s = __builtin_amdgcn_mfma_f32_16x16x32_bf16(ka1, a1, s, 0, 0, 0);
        return s;
    };

    char* PL = SM + 65536 + w * 4096;        // [16 q][128 keys] bf16, 256B rows
    const int b_ = bh >> 4, h = bh & 15;
    const int r0 = lane >> 4, cc = lane & 15;

    // pass-B body for one tile over a 128-key chunk; optionally interleaves the
    // OTHER tile's rowsum between the weight store and PV (covers store drain)
    auto passB_iter = [&](const char* kb, const char* vl, float inv,
                          const s8v& a0, const s8v& a1, float* wbase, int c,
                          f4v* acc, float* rs_other, const s8v* o0, const s8v* o1) {
        // scores -> normalized bf16 P into PL (swizzled)
#pragma unroll
        for (int st = 0; st < 8; ++st) {
            const f4v s = qk16(kb, st, a0, a1);
            f4v p;
#pragma unroll
            for (int r = 0; r < 4; ++r) p[r] = hw_exp2(s[r] * EXP_SCALE) * inv;
            const int bix = st * 2 + (g >> 1);
            const int wa = fr * 256 + (((bix ^ fr) << 4) | ((g & 1) * 8));
            *(unsigned int*)(PL + wa)     = pk2bf(p[0], p[1]);
            *(unsigned int*)(PL + wa + 4) = pk2bf(p[2], p[3]);
        }
        // cooperative NT weight store: 8 x (16 lanes x 16B = 256B contiguous)
#pragma unroll
        for (int i = 0; i < 4; ++i) {
            const int row = i * 4 + r0;
#pragma unroll
            for (int grp = 0; grp < 2; ++grp) {
                const int bir = grp * 8 + (cc >> 1);
                const u4v pw = *(const u4v*)(PL + row * 256 +
                                             (((bir ^ row) << 4) | ((cc & 1) * 8)));
                f4v o;
#pragma unroll
                for (int e = 0; e < 4; ++e) o[e] = bf2f(pw[e]);
                __builtin_nontemporal_store(o,
                    (f4v*)(wbase + (size_t)row * S_LEN + c * 128 + grp * 64 + cc * 4));
            }
        }
        // other tile's rowsum on the SAME staged K (covers store drain)
        if (rs_other) {
            float acc_rs = 0.f;
#pragma unroll
            for (int st = 0; st < 8; ++st) {
                const f4v s = qk16(kb, st, *o0, *o1);
#pragma unroll
                for (int r = 0; r < 4; ++r) acc_rs += hw_exp2(s[r] * EXP_SCALE);
            }
            *rs_other += acc_rs;
        }
        // PV: acc[tt] += P[16q x 128k] @ V[128k x 16dh]
#pragma unroll
        for (int ks = 0; ks < 4; ++ks) {
            const s8v pa = *(const s8v*)(PL + fr * 256 + (((ks * 4 + g) ^ fr) << 4));
#pragma unroll
            for (int tt = 0; tt < 4; ++tt) {
                const int vrow = tt * 16 + fr;
                const s8v vv = *(const s8v*)(vl + vrow * 256 +
                                             (((ks * 4 + g) ^ (vrow & 15)) << 4));
                acc[tt] = __builtin_amdgcn_mfma_f32_16x16x32_bf16(pa, vv, acc[tt], 0, 0, 0);
            }
        }
    };

    // ---- phase 1: rowsum(t0), DIRECT K fragment reads, barrier-free ----
    float rsum0 = 0.f;
#pragma unroll 4
    for (int ck = 0; ck < 128; ++ck) {
        const unsigned short* kr = Kp + (size_t)(ck * 16 + fr) * HEAD_D + g * 8;
        const s8v ka0 = *(const s8v*)(kr);
        const s8v ka1 = *(const s8v*)(kr + 32);
        f4v s = (f4v){0.f, 0.f, 0.f, 0.f};
        s = __builtin_amdgcn_mfma_f32_16x16x32_bf16(ka0, qa00, s, 0, 0, 0);
        s = __builtin_amdgcn_mfma_f32_16x16x32_bf16(ka1, qa01, s, 0, 0, 0);
#pragma unroll
        for (int r = 0; r < 4; ++r) rsum0 += hw_exp2(s[r] * EXP_SCALE);
    }
    asm volatile("s_waitcnt vmcnt(0)" ::: "memory");   // pin: manual counts below stay exact
    rsum0 += __shfl_xor(rsum0, 16);
    rsum0 += __shfl_xor(rsum0, 32);
    const float inv0 = 1.f / rsum0;

    // ---- phase 2: pass B(t0) + rowsum(t1) interleaved, K128+V128 (16 iters) ----
    f4v acc[4];
#pragma unroll
    for (int i = 0; i < 4; ++i) acc[i] = (f4v){0.f, 0.f, 0.f, 0.f};
    float rsum1 = 0.f;
    float* wbase0 = wts + ((size_t)bh * S_LEN + q0) * S_LEN;

    stageK128(0, SM); stageV128(0, SM + 32768);
    for (int c = 0; c < 16; ++c) {
        const int cur = c & 1;
        if (c < 15) { stageK128(c + 1, SM + (cur ^ 1) * 16384);
                      stageV128(c + 1, SM + 32768 + (cur ^ 1) * 16384); }
        if (c == 0)      asm volatile("s_waitcnt vmcnt(8)" ::: "memory");
        else if (c < 15) asm volatile("s_waitcnt vmcnt(16)" ::: "memory");
        else             asm volatile("s_waitcnt vmcnt(8)" ::: "memory");
        asm volatile("s_barrier" ::: "memory");
        passB_iter(SM + cur * 16384, SM + 32768 + cur * 16384, inv0,
                   qa00, qa01, wbase0, c, acc, &rsum1, &qa10, &qa11);
        BAR_LGKM();
    }
    rsum1 += __shfl_xor(rsum1, 16);
    rsum1 += __shfl_xor(rsum1, 32);
    const float inv1 = 1.f / rsum1;

    // epilogue t0 (already normalized), nontemporal
#pragma unroll
    for (int tt = 0; tt < 4; ++tt)
#pragma unroll
        for (int r = 0; r < 4; ++r)
            __builtin_nontemporal_store(acc[tt][r],
                &out[((size_t)b_ * S_LEN + q0 + g * 4 + r) * D_MODEL +
                     h * HEAD_D + tt * 16 + fr]);

    // ---- phase 3: pass B(t1), K128+V128 (16 iters) ----
#pragma unroll
    for (int i = 0; i < 4; ++i) acc[i] = (f4v){0.f, 0.f, 0.f, 0.f};
    float* wbase1 = wts + ((size_t)bh * S_LEN + q1) * S_LEN;

    stageK128(0, SM); stageV128(0, SM + 32768);
    for (int c = 0; c < 16; ++c) {
        const int cur = c & 1;
        if (c < 15) { stageK128(c + 1, SM + (cur ^ 1) * 16384);
                      stageV128(c + 1, SM + 32768 + (cur ^ 1) * 16384); }
        if (c == 0)      asm volatile("s_waitcnt vmcnt(8)" ::: "memory");
        else if (c < 15) asm volatile("s_waitcnt vmcnt(16)" ::: "memory");
        else             asm volatile("s_waitcnt vmcnt(8)" ::: "memory");
        asm volatile("s_barrier" ::: "memory");
        passB_iter(SM + cur * 16384, SM + 32768 + cur * 16384, inv1,
                   qa10, qa11, wbase1, c, acc, nullptr, nullptr, nullptr);
        BAR_LGKM();
    }

    // epilogue t1, nontemporal
#pragma unroll
    for (int tt = 0; tt < 4; ++tt)
#pragma unroll
        for (int r = 0; r < 4; ++r)
            __builtin_nontemporal_store(acc[tt][r],
                &out[((size_t)b_ * S_LEN + q1 + g * 4 + r) * D_MODEL +
                     h * HEAD_D + tt * 16 + fr]);
}

// ---------------- launch ----------------
extern "C" void kernel_launch(void* const* d_in, const int* in_sizes, int n_in,
                              void* d_out, int out_size, void* d_ws, size_t ws_size,
                              hipStream_t stream) {
    const float* x  = (const float*)d_in[0];
    const float* Wq = (const float*)d_in[1];
    const float* bq = (const float*)d_in[2];
    const float* Wk = (const float*)d_in[3];
    const float* bk = (const float*)d_in[4];
    const float* Wv = (const float*)d_in[5];
    const float* bv = (const float*)d_in[6];

    float* out = (float*)d_out;                              // [2,2048,1024]
    float* wts = out + (size_t)BATCH * S_LEN * D_MODEL;      // [2,16,2048,2048]

    unsigned short* xb    = (unsigned short*)d_ws;
    unsigned short* wqb   = xb  + (size_t)M_TOT * D_MODEL;
    unsigned short* wkb   = wqb + (size_t)D_MODEL * D_MODEL;
    unsigned short* wvb   = wkb + (size_t)D_MODEL * D_MODEL;
    unsigned short* q_ws  = wvb + (size_t)D_MODEL * D_MODEL;             // [b,h,s,dh]
    unsigned short* k_ws  = q_ws + (size_t)M_TOT * D_MODEL;              // [b,h,s,dh]
    unsigned short* vt_ws = k_ws + (size_t)M_TOT * D_MODEL;              // [b,h,dh,s]

    cvt_all<<<1024, 256, 0, stream>>>(x, Wq, Wk, Wv, xb, wqb, wkb, wvb);

    qkv_gemm<<<dim3(32, 8, 3), 256, 0, stream>>>(xb, wqb, wkb, wvb, bq, bk, bv,
                                                 q_ws, k_ws, vt_ws);

    attn_fused12<<<512, 256, 0, stream>>>(q_ws, k_ws, vt_ws, out, wts);
}

// Round 17
// 185.037 us; speedup vs baseline: 1.2105x; 1.2105x over previous
//
#include <hip/hip_runtime.h>
#include <stdint.h>

// Problem constants
#define S_LEN   2048
#define D_MODEL 1024
#define N_HEADS 16
#define HEAD_D  64
#define BATCH   2
#define M_TOT   (BATCH * S_LEN)   // 4096 rows for the QKV projection GEMM

typedef __attribute__((ext_vector_type(8))) short s8v;            // 8 x bf16 (MFMA A/B frag)
typedef __attribute__((ext_vector_type(4))) float f4v;            // 4 x f32  (MFMA C/D frag)
typedef __attribute__((ext_vector_type(4))) unsigned short u4v;   // 4 x bf16 packed

__device__ __forceinline__ float bf2f(unsigned short u) {
    union { unsigned int i; float f; } c; c.i = ((unsigned int)u) << 16; return c.f;
}
__device__ __forceinline__ unsigned short f2bf(float f) {
    union { float f; unsigned int i; } c; c.f = f;
    unsigned int u = c.i + 0x7FFFu + ((c.i >> 16) & 1u);   // round-nearest-even
    return (unsigned short)(u >> 16);
}
__device__ __forceinline__ unsigned int pk2bf(float lo, float hi) {
    return (unsigned int)f2bf(lo) | ((unsigned int)f2bf(hi) << 16);
}
// exp2 via the HW transcendental (v_exp_f32)
__device__ __forceinline__ float hw_exp2(float x) { return __builtin_amdgcn_exp2f(x); }

// async global->LDS, 16B per lane; LDS dest is wave-uniform base (+lane*16 implicit)
#define GLD16(gp, lp) __builtin_amdgcn_global_load_lds(                      \
    (const __attribute__((address_space(1))) void*)(const void*)(gp),        \
    (__attribute__((address_space(3))) void*)(void*)(lp), 16, 0, 0)

// barrier WITHOUT draining vmcnt (prefetches stay in flight) but WITH lgkmcnt
// drain (R5 race fix: no wave signals the barrier with ds_reads outstanding).
#define BAR_LGKM() asm volatile("s_waitcnt lgkmcnt(0)\n\ts_barrier" ::: "memory")

// exp(x*0.125) == exp2(x * 0.125*log2(e))
#define EXP_SCALE 0.1803368801111204f

// ---------------- kernel 0: fp32 -> bf16 conversion ----------------
__global__ __launch_bounds__(256) void cvt_bf16(const float* __restrict__ src,
                                                unsigned short* __restrict__ dst, int n) {
    int i = (blockIdx.x * 256 + threadIdx.x) * 4;
    int stride = gridDim.x * 1024;
    for (; i < n; i += stride) {
        float4 v = *(const float4*)(src + i);
        u4v o;
        o[0] = f2bf(v.x); o[1] = f2bf(v.y); o[2] = f2bf(v.z); o[3] = f2bf(v.w);
        *(u4v*)(dst + i) = o;
    }
}

// ---------------- kernel 1: QKV projection GEMM (m97 structure) ----------------
__global__ __launch_bounds__(256) void qkv_gemm(
    const unsigned short* __restrict__ X,
    const unsigned short* __restrict__ Wq, const unsigned short* __restrict__ Wk,
    const unsigned short* __restrict__ Wv,
    const float* __restrict__ bq, const float* __restrict__ bk, const float* __restrict__ bv,
    unsigned short* __restrict__ q_ws, unsigned short* __restrict__ k_ws,
    unsigned short* __restrict__ vt_ws) {
    __shared__ unsigned short sA[128 * 32];
    __shared__ unsigned short sB[128 * 32];

    const int z = blockIdx.z;
    const unsigned short* Wm = (z == 0) ? Wq : ((z == 1) ? Wk : Wv);
    const float* bm = (z == 0) ? bq : ((z == 1) ? bk : bv);
    const int m0 = blockIdx.x * 128, n0 = blockIdx.y * 128;
    const int t = threadIdx.x;
    const int lane = t & 63, w = t >> 6;
    const int fr = lane & 15, g = lane >> 4;
    const int wr = w >> 1, wc = w & 1;

    f4v acc[4][4];
#pragma unroll
    for (int i = 0; i < 4; ++i)
#pragma unroll
        for (int j = 0; j < 4; ++j) acc[i][j] = (f4v){0.f, 0.f, 0.f, 0.f};

    const int rowL = t >> 2;
    const int colL = (t & 3) * 8;
    const unsigned short* gA = X + (size_t)(m0 + rowL) * D_MODEL + colL;
    const unsigned short* gB = Wm + (size_t)(n0 + rowL) * D_MODEL + colL;

    for (int kb = 0; kb < 32; ++kb) {
        const int k0 = kb * 32;
        GLD16(gA + k0,                 sA + w * 512);
        GLD16(gA + 64 * D_MODEL + k0,  sA + 2048 + w * 512);
        GLD16(gB + k0,                 sB + w * 512);
        GLD16(gB + 64 * D_MODEL + k0,  sB + 2048 + w * 512);
        __syncthreads();

        s8v af[4], bfv[4];
#pragma unroll
        for (int i = 0; i < 4; ++i)
            af[i] = *(const s8v*)(sA + (wr * 64 + i * 16 + fr) * 32 + g * 8);
#pragma unroll
        for (int j = 0; j < 4; ++j)
            bfv[j] = *(const s8v*)(sB + (wc * 64 + j * 16 + fr) * 32 + g * 8);
#pragma unroll
        for (int i = 0; i < 4; ++i)
#pragma unroll
            for (int j = 0; j < 4; ++j)
                acc[i][j] = __builtin_amdgcn_mfma_f32_16x16x32_bf16(af[i], bfv[j], acc[i][j], 0, 0, 0);
        __syncthreads();
    }

    const int e_base = n0 + wc * 64;
    const int m_base = m0 + wr * 64;
    if (z < 2) {
        unsigned short* dst = (z == 0) ? q_ws : k_ws;
#pragma unroll
        for (int i = 0; i < 4; ++i) {
#pragma unroll
            for (int j = 0; j < 4; ++j) {
                const int e = e_base + j * 16 + fr;
                const int h = e >> 6, dh = e & 63;
                const float bias = bm[e];
                const int mr = m_base + i * 16 + g * 4;
                const int b_ = mr >> 11, srow = mr & 2047;
                const size_t base = (((size_t)(b_ * N_HEADS + h) * S_LEN + srow) << 6) + dh;
#pragma unroll
                for (int r = 0; r < 4; ++r)
                    dst[base + ((size_t)r << 6)] = f2bf(acc[i][j][r] + bias);
            }
        }
    } else {
#pragma unroll
        for (int i = 0; i < 4; ++i) {
#pragma unroll
            for (int j = 0; j < 4; ++j) {
                const int e = e_base + j * 16 + fr;
                const int h = e >> 6, dh = e & 63;
                const float bias = bm[e];
                const int mr = m_base + i * 16 + g * 4;
                const int b_ = mr >> 11, srow = mr & 2047;
                u4v pk;
#pragma unroll
                for (int r = 0; r < 4; ++r) pk[r] = f2bf(acc[i][j][r] + bias);
                *(u4v*)(vt_ws + ((size_t)(b_ * N_HEADS + h) * HEAD_D + dh) * S_LEN + srow) = pk;
            }
        }
    }
}

// ---------------- kernel 2: fused attention (R15 structure, converged) ----------
// R17 = exact revert to R15 (best: 185.09 us). R16's barrier-free direct-global
// phase 1 regressed -39us (R4 redux: fragment-shaped 64B-segment reads through
// the shared TA queue; staging via global_load_lds full lines is mandatory).
//  phase 1 (8 iters):  K256 chunks (2x32KB dbuf), rowsum(t0) only.
//  phase 2 (16 iters): K128+V128, pass B(t0) + rowsum(t1) interleaved.
//  phase 3 (16 iters): pass B(t1).
// Weight stores: cooperative from PL, 8 x 256B contiguous NT per lane per iter
// (R10 rule: never scatter the 540MB stream below 256B segments).
// vmcnt (m135 oldest-first): ph1 8/0; ph2,3 c==0:8, steady:16, last:8.
// LDS 80KB -> 2 WG/CU (8 waves/CU, proven sufficient in R11/R12).
__global__ __launch_bounds__(256, 2) void attn_fused11(
    const unsigned short* __restrict__ q_ws, const unsigned short* __restrict__ k_ws,
    const unsigned short* __restrict__ vt_ws,
    float* __restrict__ out, float* __restrict__ wts) {
    __shared__ __align__(16) char SM[81920];
    // phase 1: KA[buf] = SM + buf*32768          (2 x 32KB, 256-key chunks)
    // phases 2/3: K[buf] = SM + buf*16384 ; V[buf] = SM + 32768 + buf*16384
    //             PL = SM + 65536 + w*4096       ([16 q][128 keys] bf16, swizzled)

    const int t = threadIdx.x, lane = t & 63, w = t >> 6;
    const int fr = lane & 15, g = lane >> 4;
    const int blk = blockIdx.x;
    // 512 WGs: bits [2:0]=xcd, [6:3]=tile-pair, [8:7]=bh-within-xcd (bijective)
    const int bh = (blk & 7) * 4 + (blk >> 7);
    const int tp = (blk >> 3) & 15;
    const int q0 = tp * 128 + w * 16;        // tile0 rows (this wave)
    const int q1 = q0 + 64;                  // tile1 rows

    const unsigned short* Kp = k_ws + (size_t)bh * S_LEN * HEAD_D;
    const unsigned short* Vt = vt_ws + (size_t)bh * HEAD_D * S_LEN;
    const unsigned short* Qp0 = q_ws + ((size_t)bh * S_LEN + q0) * HEAD_D;
    const unsigned short* Qp1 = q_ws + ((size_t)bh * S_LEN + q1) * HEAD_D;

    const s8v qa00 = *(const s8v*)(Qp0 + fr * HEAD_D + g * 8);
    const s8v qa01 = *(const s8v*)(Qp0 + fr * HEAD_D + 32 + g * 8);
    const s8v qa10 = *(const s8v*)(Qp1 + fr * HEAD_D + g * 8);
    const s8v qa11 = *(const s8v*)(Qp1 + fr * HEAD_D + 32 + g * 8);

    // K chunks: [keys][64 dh] bf16, 128B rows, blk^=row&7 source pre-swizzle
    auto stageK128 = [&](int c, char* dst) {
#pragma unroll
        for (int j = 0; j < 4; ++j) {
            const int d = t * 16 + j * 4096;
            const int row = d >> 7, cb = (d >> 4) & 7;
            GLD16(Kp + (size_t)(c * 128 + row) * HEAD_D + ((cb ^ (row & 7)) << 3),
                  dst + w * 1024 + j * 4096);
        }
    };
    auto stageK256 = [&](int c, char* dst) {
#pragma unroll
        for (int j = 0; j < 8; ++j) {
            const int d = t * 16 + j * 4096;
            const int row = d >> 7, cb = (d >> 4) & 7;
            GLD16(Kp + (size_t)(c * 256 + row) * HEAD_D + ((cb ^ (row & 7)) << 3),
                  dst + w * 1024 + j * 4096);
        }
    };
    // V128 chunk (16KB): [64 dh][128 keys], 256B rows, blk^=row&15 pre-swizzle
    auto stageV128 = [&](int c, char* dst) {
#pragma unroll
        for (int j = 0; j < 4; ++j) {
            const int d = t * 16 + j * 4096;
            const int row = d >> 8, cb = (d >> 4) & 15;
            GLD16(Vt + (size_t)row * S_LEN + c * 128 + ((cb ^ (row & 15)) << 3),
                  dst + w * 1024 + j * 4096);
        }
    };
    // swapped QK^T, one 16-key subtile: lane(fr,g) reg r = S[key st*16+g*4+r][q=fr]
    auto qk16 = [&](const char* kb, int st, const s8v& a0, const s8v& a1) -> f4v {
        const int row = st * 16 + fr, m = row & 7;
        const s8v ka0 = *(const s8v*)(kb + row * 128 + ((g ^ m) << 4));
        const s8v ka1 = *(const s8v*)(kb + row * 128 + (((4 + g) ^ m) << 4));
        f4v s = (f4v){0.f, 0.f, 0.f, 0.f};
        s = __builtin_amdgcn_mfma_f32_16x16x32_bf16(ka0, a0, s, 0, 0, 0);
        s = __builtin_amdgcn_mfma_f32_16x16x32_bf16(ka1, a1, s, 0, 0, 0);
        return s;
    };

    char* PL = SM + 65536 + w * 4096;        // [16 q][128 keys] bf16, 256B rows
    const int b_ = bh >> 4, h = bh & 15;
    const int r0 = lane >> 4, cc = lane & 15;

    // pass-B body for one tile over a 128-key chunk; optionally interleaves the
    // OTHER tile's rowsum between the weight store and PV (covers store drain)
    auto passB_iter = [&](const char* kb, const char* vl, float inv,
                          const s8v& a0, const s8v& a1, float* wbase, int c,
                          f4v* acc, float* rs_other, const s8v* o0, const s8v* o1) {
        // scores -> normalized bf16 P into PL (swizzled)
#pragma unroll
        for (int st = 0; st < 8; ++st) {
            const f4v s = qk16(kb, st, a0, a1);
            f4v p;
#pragma unroll
            for (int r = 0; r < 4; ++r) p[r] = hw_exp2(s[r] * EXP_SCALE) * inv;
            const int bix = st * 2 + (g >> 1);
            const int wa = fr * 256 + (((bix ^ fr) << 4) | ((g & 1) * 8));
            *(unsigned int*)(PL + wa)     = pk2bf(p[0], p[1]);
            *(unsigned int*)(PL + wa + 4) = pk2bf(p[2], p[3]);
        }
        // cooperative NT weight store: 8 x (16 lanes x 16B = 256B contiguous)
#pragma unroll
        for (int i = 0; i < 4; ++i) {
            const int row = i * 4 + r0;
#pragma unroll
            for (int grp = 0; grp < 2; ++grp) {
                const int bir = grp * 8 + (cc >> 1);
                const u4v pw = *(const u4v*)(PL + row * 256 +
                                             (((bir ^ row) << 4) | ((cc & 1) * 8)));
                f4v o;
#pragma unroll
                for (int e = 0; e < 4; ++e) o[e] = bf2f(pw[e]);
                __builtin_nontemporal_store(o,
                    (f4v*)(wbase + (size_t)row * S_LEN + c * 128 + grp * 64 + cc * 4));
            }
        }
        // other tile's rowsum on the SAME staged K (covers store drain)
        if (rs_other) {
            float acc_rs = 0.f;
#pragma unroll
            for (int st = 0; st < 8; ++st) {
                const f4v s = qk16(kb, st, *o0, *o1);
#pragma unroll
                for (int r = 0; r < 4; ++r) acc_rs += hw_exp2(s[r] * EXP_SCALE);
            }
            *rs_other += acc_rs;
        }
        // PV: acc[tt] += P[16q x 128k] @ V[128k x 16dh]
#pragma unroll
        for (int ks = 0; ks < 4; ++ks) {
            const s8v pa = *(const s8v*)(PL + fr * 256 + (((ks * 4 + g) ^ fr) << 4));
#pragma unroll
            for (int tt = 0; tt < 4; ++tt) {
                const int vrow = tt * 16 + fr;
                const s8v vv = *(const s8v*)(vl + vrow * 256 +
                                             (((ks * 4 + g) ^ (vrow & 15)) << 4));
                acc[tt] = __builtin_amdgcn_mfma_f32_16x16x32_bf16(pa, vv, acc[tt], 0, 0, 0);
            }
        }
    };

    // ---- phase 1: rowsum(t0) only, K256 chunks (8 iters) ----
    float rsum0 = 0.f;
    stageK256(0, SM);
    for (int c = 0; c < 8; ++c) {
        const int cur = c & 1;
        if (c < 7) stageK256(c + 1, SM + (cur ^ 1) * 32768);
        if (c < 7) asm volatile("s_waitcnt vmcnt(8)" ::: "memory");
        else       asm volatile("s_waitcnt vmcnt(0)" ::: "memory");
        asm volatile("s_barrier" ::: "memory");
        const char* kb = SM + cur * 32768;
#pragma unroll
        for (int st = 0; st < 16; ++st) {
            const f4v s = qk16(kb, st, qa00, qa01);
#pragma unroll
            for (int r = 0; r < 4; ++r) rsum0 += hw_exp2(s[r] * EXP_SCALE);
        }
        BAR_LGKM();
    }
    rsum0 += __shfl_xor(rsum0, 16);
    rsum0 += __shfl_xor(rsum0, 32);
    const float inv0 = 1.f / rsum0;

    // ---- phase 2: pass B(t0) + rowsum(t1) interleaved, K128+V128 (16 iters) ----
    f4v acc[4];
#pragma unroll
    for (int i = 0; i < 4; ++i) acc[i] = (f4v){0.f, 0.f, 0.f, 0.f};
    float rsum1 = 0.f;
    float* wbase0 = wts + ((size_t)bh * S_LEN + q0) * S_LEN;

    stageK128(0, SM); stageV128(0, SM + 32768);
    for (int c = 0; c < 16; ++c) {
        const int cur = c & 1;
        if (c < 15) { stageK128(c + 1, SM + (cur ^ 1) * 16384);
                      stageV128(c + 1, SM + 32768 + (cur ^ 1) * 16384); }
        if (c == 0)      asm volatile("s_waitcnt vmcnt(8)" ::: "memory");
        else if (c < 15) asm volatile("s_waitcnt vmcnt(16)" ::: "memory");
        else             asm volatile("s_waitcnt vmcnt(8)" ::: "memory");
        asm volatile("s_barrier" ::: "memory");
        passB_iter(SM + cur * 16384, SM + 32768 + cur * 16384, inv0,
                   qa00, qa01, wbase0, c, acc, &rsum1, &qa10, &qa11);
        BAR_LGKM();
    }
    rsum1 += __shfl_xor(rsum1, 16);
    rsum1 += __shfl_xor(rsum1, 32);
    const float inv1 = 1.f / rsum1;

    // epilogue t0 (already normalized), nontemporal
#pragma unroll
    for (int tt = 0; tt < 4; ++tt)
#pragma unroll
        for (int r = 0; r < 4; ++r)
            __builtin_nontemporal_store(acc[tt][r],
                &out[((size_t)b_ * S_LEN + q0 + g * 4 + r) * D_MODEL +
                     h * HEAD_D + tt * 16 + fr]);

    // ---- phase 3: pass B(t1), K128+V128 (16 iters) ----
#pragma unroll
    for (int i = 0; i < 4; ++i) acc[i] = (f4v){0.f, 0.f, 0.f, 0.f};
    float* wbase1 = wts + ((size_t)bh * S_LEN + q1) * S_LEN;

    stageK128(0, SM); stageV128(0, SM + 32768);
    for (int c = 0; c < 16; ++c) {
        const int cur = c & 1;
        if (c < 15) { stageK128(c + 1, SM + (cur ^ 1) * 16384);
                      stageV128(c + 1, SM + 32768 + (cur ^ 1) * 16384); }
        if (c == 0)      asm volatile("s_waitcnt vmcnt(8)" ::: "memory");
        else if (c < 15) asm volatile("s_waitcnt vmcnt(16)" ::: "memory");
        else             asm volatile("s_waitcnt vmcnt(8)" ::: "memory");
        asm volatile("s_barrier" ::: "memory");
        passB_iter(SM + cur * 16384, SM + 32768 + cur * 16384, inv1,
                   qa10, qa11, wbase1, c, acc, nullptr, nullptr, nullptr);
        BAR_LGKM();
    }

    // epilogue t1, nontemporal
#pragma unroll
    for (int tt = 0; tt < 4; ++tt)
#pragma unroll
        for (int r = 0; r < 4; ++r)
            __builtin_nontemporal_store(acc[tt][r],
                &out[((size_t)b_ * S_LEN + q1 + g * 4 + r) * D_MODEL +
                     h * HEAD_D + tt * 16 + fr]);
}

// ---------------- launch ----------------
extern "C" void kernel_launch(void* const* d_in, const int* in_sizes, int n_in,
                              void* d_out, int out_size, void* d_ws, size_t ws_size,
                              hipStream_t stream) {
    const float* x  = (const float*)d_in[0];
    const float* Wq = (const float*)d_in[1];
    const float* bq = (const float*)d_in[2];
    const float* Wk = (const float*)d_in[3];
    const float* bk = (const float*)d_in[4];
    const float* Wv = (const float*)d_in[5];
    const float* bv = (const float*)d_in[6];

    float* out = (float*)d_out;                              // [2,2048,1024]
    float* wts = out + (size_t)BATCH * S_LEN * D_MODEL;      // [2,16,2048,2048]

    unsigned short* xb    = (unsigned short*)d_ws;
    unsigned short* wqb   = xb  + (size_t)M_TOT * D_MODEL;
    unsigned short* wkb   = wqb + (size_t)D_MODEL * D_MODEL;
    unsigned short* wvb   = wkb + (size_t)D_MODEL * D_MODEL;
    unsigned short* q_ws  = wvb + (size_t)D_MODEL * D_MODEL;             // [b,h,s,dh]
    unsigned short* k_ws  = q_ws + (size_t)M_TOT * D_MODEL;              // [b,h,s,dh]
    unsigned short* vt_ws = k_ws + (size_t)M_TOT * D_MODEL;              // [b,h,dh,s]

    cvt_bf16<<<1024, 256, 0, stream>>>(x,  xb,  M_TOT * D_MODEL);
    cvt_bf16<<<256,  256, 0, stream>>>(Wq, wqb, D_MODEL * D_MODEL);
    cvt_bf16<<<256,  256, 0, stream>>>(Wk, wkb, D_MODEL * D_MODEL);
    cvt_bf16<<<256,  256, 0, stream>>>(Wv, wvb, D_MODEL * D_MODEL);

    qkv_gemm<<<dim3(32, 8, 3), 256, 0, stream>>>(xb, wqb, wkb, wvb, bq, bk, bv,
                                                 q_ws, k_ws, vt_ws);

    attn_fused11<<<512, 256, 0, stream>>>(q_ws, k_ws, vt_ws, out, wts);
}